// Round 8
// baseline (143.680 us; speedup 1.0000x reference)
//
#include <hip/hip_runtime.h>
#include <math.h>

// Problem constants
#define BATCH 64
#define SEQL  512
#define DIN   256
#define NF    256
#define KS    3
#define KF    (KS * NF)        // 768

// Combined-channel formulation:
//   Xcat[b,lp,ch] (lp = l+1, rows 0 and 513 zero):
//     ch<256 -> bf16(x[b,l,ch]) ; ch>=256 -> Y[b,l,ch-256] = (x@U)*sigmoid(z)
//   out[b,l,f] = relu( sum_{k,ch} Xc[b][l+k][ch] * WcT[f][k*512+ch] + bias[f] )
#define XCH 512
#define XL  (SEQL + 2)
#define KC  (KS * XCH)          // 1536
#define AR2 72                  // stage2 A halo rows staged (66 used, 9 gl_lds calls)

typedef __attribute__((ext_vector_type(8))) short short8;
typedef __attribute__((ext_vector_type(4))) float floatx4;
typedef __attribute__((ext_vector_type(8))) unsigned short ushort8v;

static __device__ __forceinline__ unsigned short f2bf(float f) {
    unsigned int u = __float_as_uint(f);
    return (unsigned short)((u + 0x7FFF + ((u >> 16) & 1)) >> 16);  // RTNE
}

// async 16B/lane global->LDS; LDS dst = wave-uniform base + lane*16
static __device__ __forceinline__ void gl_lds16(const void* g, void* l) {
    __builtin_amdgcn_global_load_lds(
        (const __attribute__((address_space(1))) unsigned int*)g,
        (__attribute__((address_space(3))) unsigned int*)l, 16, 0, 0);
}

// ---------------------------------------------------------------------------
// pack: WcT[f][c] transpose (96 blk) + UT[e][d] transpose (16 blk).
// 112 blocks x 256 threads.
// ---------------------------------------------------------------------------
__global__ __launch_bounds__(256) void pack_kernel(
    const float* __restrict__ U, const float* __restrict__ V,
    const float* __restrict__ Bw,
    unsigned short* __restrict__ WcT, unsigned short* __restrict__ UT)
{
    const int blk = blockIdx.x;
    const int t   = threadIdx.x;
    __shared__ unsigned short tile[64][64 + 2];

    if (blk < 96) {
        const int f0 = (blk & 3) * 64, c0 = (blk >> 2) * 64;
        const int fl = t & 63, cb = t >> 6;
        #pragma unroll
        for (int it = 0; it < 16; ++it) {
            const int cl = cb + it * 4;
            const int c  = c0 + cl;
            const int k  = c >> 9, ch = c & (XCH - 1);
            const float v = (ch < DIN) ? Bw[(size_t)ch * KF + k * NF + f0 + fl]
                                       : V[(size_t)(ch - DIN) * KF + k * NF + f0 + fl];
            tile[cl][fl] = f2bf(v);
        }
        __syncthreads();
        const int cl2 = t & 63, fb = t >> 6;
        #pragma unroll
        for (int it = 0; it < 16; ++it) {
            const int fl2 = fb + it * 4;
            WcT[(size_t)(f0 + fl2) * KC + c0 + cl2] = tile[cl2][fl2];
        }
    } else {
        const int bb = blk - 96;
        const int e0 = (bb & 3) * 64, d0 = (bb >> 2) * 64;
        const int el = t & 63, db = t >> 6;
        #pragma unroll
        for (int it = 0; it < 16; ++it) {
            const int dl = db + it * 4;
            tile[dl][el] = f2bf(U[(size_t)(d0 + dl) * DIN + e0 + el]);
        }
        __syncthreads();
        const int dl2 = t & 63, eb = t >> 6;
        #pragma unroll
        for (int it = 0; it < 16; ++it) {
            const int el2 = eb + it * 4;
            UT[(size_t)(e0 + el2) * DIN + d0 + dl2] = tile[dl2][el2];
        }
    }
}

// ---------------------------------------------------------------------------
// stage1: Y = (x@U)*sigmoid(z) -> Xc Y-half; also writes bf16 x-half and the
// zero pad rows. M=64 l-rows, N=256 e (full, 64/wave), BK=64 (K=256).
// Grid 512 x 256. LDS 40 KB -> 3 blocks/CU. Single x read (no duplication).
// ---------------------------------------------------------------------------
__global__ __launch_bounds__(256, 3) void stage1_kernel(
    const float* __restrict__ x, const unsigned short* __restrict__ UT,
    const float* __restrict__ z, unsigned short* __restrict__ Xc)
{
    __shared__ unsigned short sh[20480];   // 40 KB: As 64x64 | Bs 256x64
    unsigned short* As = sh;               // [64 rows][64 shorts]
    unsigned short* Bs = sh + 4096;        // [256 rows][64 shorts]

    const int tid  = threadIdx.x;
    const int lane = tid & 63;
    const int wave = tid >> 6;
    const int quad = lane >> 4, l16 = lane & 15;
    const int r8   = lane >> 3;            // staging row-in-call
    const int ud8  = lane & 7;             // staging dst 16B unit
    const int ugs  = ud8 ^ r8;             // swizzled src unit (row&7 == r8)

    const int b     = blockIdx.x >> 3;
    const int lbase = (blockIdx.x & 7) * 64;

    // zero pad rows (once per batch: first/last l-tile blocks)
    if ((blockIdx.x & 7) == 0 && wave == 0) {
        uint4 zz = {0u, 0u, 0u, 0u};
        *(uint4*)&Xc[(size_t)b * XL * XCH + lane * 8] = zz;
    }
    if ((blockIdx.x & 7) == 7 && wave == 3) {
        uint4 zz = {0u, 0u, 0u, 0u};
        *(uint4*)&Xc[((size_t)b * XL + XL - 1) * XCH + lane * 8] = zz;
    }

    floatx4 acc[4][4] = {};

    for (int k0 = 0; k0 < DIN; k0 += 64) {
        // B tile: UT rows 0..255, cols k0..k0+63 (64 rows/wave, 8 calls)
        #pragma unroll
        for (int c = 0; c < 8; ++c) {
            const int row = wave * 64 + c * 8 + r8;
            gl_lds16(UT + (size_t)row * DIN + k0 + ugs * 8,
                     Bs + (size_t)(wave * 64 + c * 8) * 64);
        }
        // A tile: fp32 x -> bf16 LDS + Xc x-half (each d written exactly once)
        #pragma unroll
        for (int it = 0; it < 2; ++it) {
            const int idx = tid + it * 256;     // 0..511 16B units
            const int row = idx >> 3;
            const int u   = idx & 7;
            const int ug  = u ^ (row & 7);
            const float* xp =
                x + ((size_t)b * SEQL + lbase + row) * DIN + k0 + ug * 8;
            const float4 v0 = *(const float4*)xp;
            const float4 v1 = *(const float4*)(xp + 4);
            ushort8v h;
            h[0] = f2bf(v0.x); h[1] = f2bf(v0.y); h[2] = f2bf(v0.z); h[3] = f2bf(v0.w);
            h[4] = f2bf(v1.x); h[5] = f2bf(v1.y); h[6] = f2bf(v1.z); h[7] = f2bf(v1.w);
            *(ushort8v*)&As[row * 64 + u * 8] = h;
            *(ushort8v*)&Xc[((size_t)b * XL + lbase + 1 + row) * XCH + k0 + ug * 8] = h;
        }
        __syncthreads();

        #pragma unroll
        for (int ks = 0; ks < 2; ++ks) {
            short8 af[4], bfr[4];
            #pragma unroll
            for (int i = 0; i < 4; ++i) {
                const int m = i * 16 + l16;
                af[i] = *(const short8*)&As[m * 64 + (((ks * 4 + quad) ^ (m & 7)) * 8)];
            }
            #pragma unroll
            for (int j = 0; j < 4; ++j) {
                const int n = wave * 64 + j * 16 + l16;
                bfr[j] = *(const short8*)&Bs[n * 64 + (((ks * 4 + quad) ^ (n & 7)) * 8)];
            }
            #pragma unroll
            for (int i = 0; i < 4; ++i)
                #pragma unroll
                for (int j = 0; j < 4; ++j)
                    acc[i][j] = __builtin_amdgcn_mfma_f32_16x16x32_bf16(
                        af[i], bfr[j], acc[i][j], 0, 0, 0);
        }
        __syncthreads();
    }

    // epilogue: sigmoid scale, transpose via LDS ([64][264] bf16), 16B stores
    #pragma unroll
    for (int j = 0; j < 4; ++j) {
        const int e = wave * 64 + j * 16 + l16;
        const float zf = 1.0f / (1.0f + expf(-z[(size_t)b * DIN + e]));
        #pragma unroll
        for (int i = 0; i < 4; ++i) {
            const int m = i * 16 + quad * 4;
            #pragma unroll
            for (int r = 0; r < 4; ++r)
                sh[(m + r) * 264 + e] = f2bf(acc[i][j][r] * zf);
        }
    }
    __syncthreads();
    #pragma unroll
    for (int it = 0; it < 8; ++it) {
        const int idx = tid + it * 256;         // 0..2047
        const int row = idx >> 5;
        const int u   = idx & 31;
        *(ushort8v*)&Xc[((size_t)b * XL + lbase + 1 + row) * XCH + DIN + u * 8] =
            *(const ushort8v*)&sh[row * 264 + u * 8];
    }
}

// ---------------------------------------------------------------------------
// stage2: out = relu(conv(Xc) + bias). M=64 l-rows, N=256 f (full, 64/wave).
// K: 8 ch-groups (64) x 3 taps x 64c. A halo (72x64, 8.7 KB) staged once per
// group; taps shift the LDS row. Wave-tile 64x64 -> 8 ds_read per 16 MFMA
// (2x better LDS intensity than R7). LDS 41 KB -> 3 blocks/CU. Grid 512.
// ---------------------------------------------------------------------------
__global__ __launch_bounds__(256, 3) void stage2_kernel(
    const unsigned short* __restrict__ Xc,
    const unsigned short* __restrict__ WcT,
    const float* __restrict__ bias, float* __restrict__ out)
{
    __shared__ unsigned short As[AR2 * 64];   // 8.7 KB  [72 rows][64 shorts]
    __shared__ unsigned short Bs[256 * 64];   // 32 KB   [256 f][64 shorts]

    const int tid  = threadIdx.x;
    const int lane = tid & 63;
    const int wave = tid >> 6;
    const int quad = lane >> 4, l16 = lane & 15;
    const int r8   = lane >> 3;
    const int ud8  = lane & 7;
    const int ugs  = ud8 ^ r8;

    const int b     = blockIdx.x >> 3;
    const int lbase = (blockIdx.x & 7) * 64;

    const unsigned short* gA = Xc + ((size_t)b * XL + lbase) * XCH;

    floatx4 acc[4][4] = {};

    #pragma unroll 1
    for (int g = 0; g < 8; ++g) {                 // 64-channel group
        // stage A rows 0..71 (lp = lbase+r), cols g*64..+63: 9 calls, ci%4==wave
        #pragma unroll
        for (int ci = 0; ci < 9; ++ci) {
            if ((ci & 3) == wave)
                gl_lds16(gA + (size_t)(ci * 8 + r8) * XCH + g * 64 + ugs * 8,
                         As + (size_t)(ci * 8) * 64);
        }
        #pragma unroll 1
        for (int tap = 0; tap < KS; ++tap) {
            // stage B: WcT rows 0..255, cols tap*512 + g*64 .. +63
            #pragma unroll
            for (int c = 0; c < 8; ++c) {
                const int row = wave * 64 + c * 8 + r8;
                gl_lds16(WcT + (size_t)row * KC + tap * XCH + g * 64 + ugs * 8,
                         Bs + (size_t)(wave * 64 + c * 8) * 64);
            }
            __syncthreads();

            #pragma unroll
            for (int ks = 0; ks < 2; ++ks) {
                short8 af[4], bfr[4];
                #pragma unroll
                for (int i = 0; i < 4; ++i) {
                    const int rr = i * 16 + l16 + tap;   // LDS row shift by tap
                    af[i] = *(const short8*)
                        &As[rr * 64 + (((ks * 4 + quad) ^ (rr & 7)) * 8)];
                }
                #pragma unroll
                for (int j = 0; j < 4; ++j) {
                    const int n = wave * 64 + j * 16 + l16;
                    bfr[j] = *(const short8*)
                        &Bs[n * 64 + (((ks * 4 + quad) ^ (n & 7)) * 8)];
                }
                #pragma unroll
                for (int i = 0; i < 4; ++i)
                    #pragma unroll
                    for (int j = 0; j < 4; ++j)
                        acc[i][j] = __builtin_amdgcn_mfma_f32_16x16x32_bf16(
                            af[i], bfr[j], acc[i][j], 0, 0, 0);
            }
            __syncthreads();
        }
    }

    #pragma unroll
    for (int j = 0; j < 4; ++j) {
        const int f  = wave * 64 + j * 16 + l16;
        const float bv = bias[f];
        #pragma unroll
        for (int i = 0; i < 4; ++i) {
            const int lrow = lbase + i * 16 + quad * 4;
            #pragma unroll
            for (int r = 0; r < 4; ++r) {
                const float v = acc[i][j][r] + bv;
                out[((size_t)b * SEQL + lrow + r) * NF + f] = fmaxf(v, 0.0f);
            }
        }
    }
}

extern "C" void kernel_launch(void* const* d_in, const int* in_sizes, int n_in,
                              void* d_out, int out_size, void* d_ws, size_t ws_size,
                              hipStream_t stream) {
    const float* x    = (const float*)d_in[0];
    const float* z    = (const float*)d_in[1];
    const float* U    = (const float*)d_in[2];
    const float* V    = (const float*)d_in[3];
    const float* Bw   = (const float*)d_in[4];
    const float* bias = (const float*)d_in[5];

    unsigned short* Xc  = (unsigned short*)d_ws;          // 64*514*512*2 B
    unsigned short* WcT = Xc + (size_t)BATCH * XL * XCH;  // 256*1536*2 B
    unsigned short* UT  = WcT + (size_t)NF * KC;          // 256*256*2 B
    float* out = (float*)d_out;

    pack_kernel<<<dim3(112), 256, 0, stream>>>(U, V, Bw, WcT, UT);
    stage1_kernel<<<dim3(512), 256, 0, stream>>>(x, UT, z, Xc);
    stage2_kernel<<<dim3(512), 256, 0, stream>>>(Xc, WcT, bias, out);
}